// Round 1
// baseline (315.359 us; speedup 1.0000x reference)
//
#include <hip/hip_runtime.h>
#include <hip/hip_bf16.h>
#include <cstdint>

typedef unsigned int uint;
typedef unsigned short ushort_t;

typedef __attribute__((ext_vector_type(8))) short short8;
typedef __attribute__((ext_vector_type(4))) short short4_t;
typedef __attribute__((ext_vector_type(4))) float float4_t;

#define NEMBD 1024
#define VOCAB 32000
#define NQ 4096
#define CHUNKS 1000   // VOCAB / 32
#define LOG2E 1.4426950408889634f

__device__ __forceinline__ ushort_t f2bf_rne(float f) {
    uint u = __float_as_uint(f);
    u += 0x7fffu + ((u >> 16) & 1u);
    return (ushort_t)(u >> 16);
}

// K1a: S[h,v] = sum_d vocab_emb[v, h*32+d], stored as ST[v*32+h] in bf16.
// One block per vocab row; 256 threads x float4 = 1024 floats (full row).
__global__ void k_build_st(const float* __restrict__ ve, ushort_t* __restrict__ ST) {
    int v = blockIdx.x;
    int t = threadIdx.x;
    const float4* row = (const float4*)(ve + (size_t)v * NEMBD);
    float4 f = row[t];
    float s = f.x + f.y + f.z + f.w;
    s += __shfl_down(s, 4, 8);
    s += __shfl_down(s, 2, 8);
    s += __shfl_down(s, 1, 8);
    if ((t & 7) == 0) ST[v * 32 + (t >> 3)] = f2bf_rne(s);
}

// K1b: pack PV B-operand fragments (16x16x16 layout, k = quad*4+j):
// S2[((c*2+f)*64 + lane)*8 + t*4 + j] = ST[(c*32 + t*16 + quad*4 + j)*32 + f*16 + lo]
__global__ void k_build_s2(const ushort_t* __restrict__ ST, ushort_t* __restrict__ S2) {
    int tid = blockIdx.x * 256 + threadIdx.x;   // 128000 total
    int l = tid & 63, f = (tid >> 6) & 1, c = tid >> 7;
    int quad = l >> 4, lo = l & 15;
    uint w[4];
    #pragma unroll
    for (int t = 0; t < 2; t++) {
        #pragma unroll
        for (int jj = 0; jj < 2; jj++) {
            ushort_t v0 = ST[(c * 32 + t * 16 + quad * 4 + jj * 2 + 0) * 32 + f * 16 + lo];
            ushort_t v1 = ST[(c * 32 + t * 16 + quad * 4 + jj * 2 + 1) * 32 + f * 16 + lo];
            w[t * 2 + jj] = (uint)v0 | ((uint)v1 << 16);
        }
    }
    uint4* dst = (uint4*)S2;
    dst[tid] = make_uint4(w[0], w[1], w[2], w[3]);
}

// K0: q1[i*32+d] = (x[i]·W_ffn[d] + b_ffn[d]) * log2(e) / max(temps[n],0.1)
__global__ void k_q1(const float* __restrict__ x, const float* __restrict__ W,
                     const float* __restrict__ b, const float* __restrict__ temps,
                     float* __restrict__ q1) {
    int tid = blockIdx.x * 256 + threadIdx.x;   // 131072
    int i = tid >> 5, d = tid & 31, n = i & 31;
    const float* xr = x + i * 32;
    float s = b[d];
    #pragma unroll
    for (int h = 0; h < 32; h++) s += xr[h] * W[d * 32 + h];
    q1[tid] = s * (LOG2E / fmaxf(temps[n], 0.1f));
}

// K2: partial flash projection. Grid 256 = 32 q-groups x 8 vocab-splits, 512 thr.
// Each wave: all 8 q-subtiles (M=128 per block) for its share of vocab chunks.
__launch_bounds__(512)
__global__ void k_proj(const ushort_t* __restrict__ ST, const ushort_t* __restrict__ S2,
                       const float* __restrict__ q, float* __restrict__ pN,
                       float* __restrict__ pD) {
    int g = blockIdx.x >> 3, p = blockIdx.x & 7;
    int wave = threadIdx.x >> 6, lane = threadIdx.x & 63;
    int quad = lane >> 4, lo = lane & 15;

    // Q fragments (B-operand of 16x16x32: n=lo (query), k=quad*8+j (dim))
    short8 qf[8];
    #pragma unroll
    for (int s = 0; s < 8; s++) {
        const float* qp = q + ((g * 128 + s * 16 + lo) * 32 + quad * 8);
        short8 v;
        #pragma unroll
        for (int j = 0; j < 8; j++) v[j] = (short)f2bf_rne(qp[j]);
        qf[s] = v;
    }

    float4_t pv0[8], pv1[8], dq[8];
    #pragma unroll
    for (int s = 0; s < 8; s++) {
        pv0[s] = (float4_t){0.f, 0.f, 0.f, 0.f};
        pv1[s] = (float4_t){0.f, 0.f, 0.f, 0.f};
        dq[s]  = (float4_t){0.f, 0.f, 0.f, 0.f};
    }
    const short4_t ones = {(short)0x3F80, (short)0x3F80, (short)0x3F80, (short)0x3F80};
    const float4_t zero4 = (float4_t){0.f, 0.f, 0.f, 0.f};

    for (int k = wave; k < 125; k += 8) {
        int c = p * 125 + k;
        // QK A-operand (16x16x32: m=lo (vocab row), k=quad*8+j (dim)); 16B contiguous
        const ushort_t* pa = ST + ((c * 32 + lo) * 32 + quad * 8);
        short8 a0 = *(const short8*)pa;             // v-tile 0 (v0..15)
        short8 a1 = *(const short8*)(pa + 512);     // v-tile 1 (v16..31)
        const ushort_t* pb = S2 + ((size_t)(c * 2) * 64 + lane) * 8;
        short8 sb0 = *(const short8*)pb;            // h 0..15  [t0 j0..3 | t1 j0..3]
        short8 sb1 = *(const short8*)(pb + 512);    // h 16..31
        short4_t b00 = {sb0[0], sb0[1], sb0[2], sb0[3]};
        short4_t b01 = {sb0[4], sb0[5], sb0[6], sb0[7]};
        short4_t b10 = {sb1[0], sb1[1], sb1[2], sb1[3]};
        short4_t b11 = {sb1[4], sb1[5], sb1[6], sb1[7]};

        #pragma unroll
        for (int s = 0; s < 8; s++) {
            // logits transposed: D[v][q], C-layout row=v=quad*4+reg, col=q=lo
            float4_t l0 = __builtin_amdgcn_mfma_f32_16x16x32_bf16(a0, qf[s], zero4, 0, 0, 0);
            float4_t l1 = __builtin_amdgcn_mfma_f32_16x16x32_bf16(a1, qf[s], zero4, 0, 0, 0);
            // exp2 (q pre-scaled by log2e/temp); C reg r == A-frag element j for K=16 MFMA
            float e0 = exp2f(l0[0]), e1 = exp2f(l0[1]), e2 = exp2f(l0[2]), e3 = exp2f(l0[3]);
            float f0 = exp2f(l1[0]), f1 = exp2f(l1[1]), f2 = exp2f(l1[2]), f3 = exp2f(l1[3]);
            uint u0 = __builtin_amdgcn_perm(__float_as_uint(e1), __float_as_uint(e0), 0x07060302u);
            uint u1 = __builtin_amdgcn_perm(__float_as_uint(e3), __float_as_uint(e2), 0x07060302u);
            uint u2 = __builtin_amdgcn_perm(__float_as_uint(f1), __float_as_uint(f0), 0x07060302u);
            uint u3 = __builtin_amdgcn_perm(__float_as_uint(f3), __float_as_uint(f2), 0x07060302u);
            union { uint u[2]; short4_t s4; } c0, c1;
            c0.u[0] = u0; c0.u[1] = u1;
            c1.u[0] = u2; c1.u[1] = u3;
            short4_t P0 = c0.s4, P1 = c1.s4;
            // PV: out[q][h] += P[q][v] * S[v][h]  (16x16x16, K=16 per v-tile)
            pv0[s] = __builtin_amdgcn_mfma_f32_16x16x16bf16_1k(P0, b00, pv0[s], 0, 0, 0);
            pv0[s] = __builtin_amdgcn_mfma_f32_16x16x16bf16_1k(P1, b01, pv0[s], 0, 0, 0);
            pv1[s] = __builtin_amdgcn_mfma_f32_16x16x16bf16_1k(P0, b10, pv1[s], 0, 0, 0);
            pv1[s] = __builtin_amdgcn_mfma_f32_16x16x16bf16_1k(P1, b11, pv1[s], 0, 0, 0);
            // denominator: D[q] += sum_v P[q][v]  (ones-B MFMA, C aligns with pv rows)
            dq[s] = __builtin_amdgcn_mfma_f32_16x16x16bf16_1k(P0, ones, dq[s], 0, 0, 0);
            dq[s] = __builtin_amdgcn_mfma_f32_16x16x16bf16_1k(P1, ones, dq[s], 0, 0, 0);
        }
    }

    // in-block reduction over 8 waves, one subtile at a time (24 KB LDS)
    __shared__ float red[8][64][12];
    int gp = blockIdx.x;
    for (int s = 0; s < 8; s++) {
        #pragma unroll
        for (int r = 0; r < 4; r++) {
            red[wave][lane][r]     = pv0[s][r];
            red[wave][lane][4 + r] = pv1[s][r];
            red[wave][lane][8 + r] = dq[s][r];
        }
        __syncthreads();
        if (wave == 0) {
            #pragma unroll
            for (int r = 0; r < 4; r++) {
                float n0 = 0.f, n1 = 0.f, dd = 0.f;
                #pragma unroll
                for (int w = 0; w < 8; w++) {
                    n0 += red[w][lane][r];
                    n1 += red[w][lane][4 + r];
                    dd += red[w][lane][8 + r];
                }
                int ql = s * 16 + quad * 4 + r;
                pN[(size_t)gp * 4096 + ql * 32 + lo]      = n0;
                pN[(size_t)gp * 4096 + ql * 32 + 16 + lo] = n1;
                if (lo == 0) pD[gp * 128 + ql] = dd;
            }
        }
        __syncthreads();
    }
}

// K3: reduce proj1 partials, apply refinement gate, emit q2 (pre-scaled).
__global__ void k_refine(const float* __restrict__ pN, const float* __restrict__ pD,
                         const float* __restrict__ x,
                         const float* __restrict__ Wr, const float* __restrict__ br,
                         const float* __restrict__ Wg, const float* __restrict__ bg,
                         const float* __restrict__ temps, float* __restrict__ q2) {
    int tid = blockIdx.x * 256 + threadIdx.x;   // 131072
    int i = tid >> 5, h = tid & 31, n = i & 31;
    int g = i >> 7, ql = i & 127;
    float N = 0.f, D = 0.f;
    #pragma unroll
    for (int p = 0; p < 8; p++) {
        N += pN[((size_t)(g * 8 + p)) * 4096 + ql * 32 + h];
        D += pD[(g * 8 + p) * 128 + ql];
    }
    float vo = N / D;
    const float* xr = x + i * 32;
    float sr = br[h], sg = bg[h];
    #pragma unroll
    for (int h2 = 0; h2 < 32; h2++) {
        sr += xr[h2] * Wr[h * 32 + h2];
        sg += xr[h2] * Wg[h * 32 + h2];
    }
    float ref  = tanhf(sr);
    float gate = 1.f / (1.f + __expf(-sg));
    float refined = vo * (1.f - gate) + ref * gate;
    q2[tid] = refined * (LOG2E / fmaxf(temps[n], 0.1f));
}

// K5: reduce proj2 partials, write final fp32 output.
__global__ void k_final(const float* __restrict__ pN, const float* __restrict__ pD,
                        float* __restrict__ out) {
    int tid = blockIdx.x * 256 + threadIdx.x;   // 131072
    int i = tid >> 5, h = tid & 31;
    int g = i >> 7, ql = i & 127;
    float N = 0.f, D = 0.f;
    #pragma unroll
    for (int p = 0; p < 8; p++) {
        N += pN[((size_t)(g * 8 + p)) * 4096 + ql * 32 + h];
        D += pD[(g * 8 + p) * 128 + ql];
    }
    out[tid] = N / D;
}

extern "C" void kernel_launch(void* const* d_in, const int* in_sizes, int n_in,
                              void* d_out, int out_size, void* d_ws, size_t ws_size,
                              hipStream_t stream) {
    const float* x     = (const float*)d_in[0];
    const float* ve    = (const float*)d_in[1];
    const float* Wf    = (const float*)d_in[2];
    const float* bf    = (const float*)d_in[3];
    const float* temps = (const float*)d_in[4];
    const float* Wr    = (const float*)d_in[5];
    const float* br    = (const float*)d_in[6];
    const float* Wg    = (const float*)d_in[7];
    const float* bg    = (const float*)d_in[8];
    float* out = (float*)d_out;

    char* ws = (char*)d_ws;
    ushort_t* ST = (ushort_t*)ws;                          // 2,048,000 B
    ushort_t* S2 = (ushort_t*)(ws + 2048000);              // 2,048,000 B
    float* q1 = (float*)(ws + 4096000);                    //   524,288 B
    float* q2 = (float*)(ws + 4096000 + 524288);           //   524,288 B
    float* pN = (float*)(ws + 4096000 + 2 * 524288);       // 4,194,304 B
    float* pD = (float*)(ws + 4096000 + 2 * 524288 + 4194304); // 131,072 B

    k_build_st<<<dim3(VOCAB), dim3(256), 0, stream>>>(ve, ST);
    k_build_s2<<<dim3(500), dim3(256), 0, stream>>>(ST, S2);
    k_q1<<<dim3(512), dim3(256), 0, stream>>>(x, Wf, bf, temps, q1);
    k_proj<<<dim3(256), dim3(512), 0, stream>>>(ST, S2, q1, pN, pD);
    k_refine<<<dim3(512), dim3(256), 0, stream>>>(pN, pD, x, Wr, br, Wg, bg, temps, q2);
    k_proj<<<dim3(256), dim3(512), 0, stream>>>(ST, S2, q2, pN, pD);
    k_final<<<dim3(512), dim3(256), 0, stream>>>(pN, pD, out);
}

// Round 2
// 266.439 us; speedup vs baseline: 1.1836x; 1.1836x over previous
//
#include <hip/hip_runtime.h>
#include <hip/hip_bf16.h>
#include <cstdint>

typedef unsigned int uint;
typedef unsigned short ushort_t;

typedef __attribute__((ext_vector_type(8))) short short8;
typedef __attribute__((ext_vector_type(4))) short short4_t;
typedef __attribute__((ext_vector_type(4))) float float4_t;

#define NEMBD 1024
#define VOCAB 32000
#define LOG2E 1.4426950408889634f

__device__ __forceinline__ ushort_t f2bf_rne(float f) {
    uint u = __float_as_uint(f);
    u += 0x7fffu + ((u >> 16) & 1u);
    return (ushort_t)(u >> 16);
}

// K1a: S[h,v] = sum_d vocab_emb[v, h*32+d], stored as ST[v*32+h] in bf16.
__global__ void k_build_st(const float* __restrict__ ve, ushort_t* __restrict__ ST) {
    int v = blockIdx.x;
    int t = threadIdx.x;
    const float4* row = (const float4*)(ve + (size_t)v * NEMBD);
    float4 f = row[t];
    float s = f.x + f.y + f.z + f.w;
    s += __shfl_down(s, 4, 8);
    s += __shfl_down(s, 2, 8);
    s += __shfl_down(s, 1, 8);
    if ((t & 7) == 0) ST[v * 32 + (t >> 3)] = f2bf_rne(s);
}

// K1b: pack PV B-operand fragments (16x16x16 layout, k = quad*4+j)
__global__ void k_build_s2(const ushort_t* __restrict__ ST, ushort_t* __restrict__ S2) {
    int tid = blockIdx.x * 256 + threadIdx.x;   // 128000 total
    int l = tid & 63, f = (tid >> 6) & 1, c = tid >> 7;
    int quad = l >> 4, lo = l & 15;
    uint w[4];
    #pragma unroll
    for (int t = 0; t < 2; t++) {
        #pragma unroll
        for (int jj = 0; jj < 2; jj++) {
            ushort_t v0 = ST[(c * 32 + t * 16 + quad * 4 + jj * 2 + 0) * 32 + f * 16 + lo];
            ushort_t v1 = ST[(c * 32 + t * 16 + quad * 4 + jj * 2 + 1) * 32 + f * 16 + lo];
            w[t * 2 + jj] = (uint)v0 | ((uint)v1 << 16);
        }
    }
    uint4* dst = (uint4*)S2;
    dst[tid] = make_uint4(w[0], w[1], w[2], w[3]);
}

// K0: q1[i*32+d] = bf16((x[i]·W_ffn[d] + b_ffn[d]) * log2e / max(temps[n],0.1))
__global__ void k_q1(const float* __restrict__ x, const float* __restrict__ W,
                     const float* __restrict__ b, const float* __restrict__ temps,
                     ushort_t* __restrict__ q1) {
    int tid = blockIdx.x * 256 + threadIdx.x;   // 131072
    int i = tid >> 5, d = tid & 31, n = i & 31;
    const float* xr = x + i * 32;
    float s = b[d];
    #pragma unroll
    for (int h = 0; h < 32; h++) s += xr[h] * W[d * 32 + h];
    q1[tid] = f2bf_rne(s * (LOG2E / fmaxf(temps[n], 0.1f)));
}

// K2: partial flash projection. Grid 1024 = 64 q-groups (64 rows) x 16 splits,
// 256 threads (4 waves, 4 q-subtiles per wave). 4 blocks/CU, 4 waves/SIMD.
__launch_bounds__(256, 4)
__global__ void k_proj(const ushort_t* __restrict__ ST, const ushort_t* __restrict__ S2,
                       const ushort_t* __restrict__ q, float* __restrict__ pN,
                       float* __restrict__ pD) {
    int g = blockIdx.x >> 4, p = blockIdx.x & 15;
    int wave = threadIdx.x >> 6, lane = threadIdx.x & 63;
    int quad = lane >> 4, lo = lane & 15;

    // Q fragments (B-operand of 16x16x32: n=lo (query row), k=quad*8+j)
    short8 qf[4];
    #pragma unroll
    for (int s = 0; s < 4; s++)
        qf[s] = *(const short8*)(q + ((g * 64 + s * 16 + lo) * 32 + quad * 8));

    float4_t pv0[4], pv1[4];
    float dsum[4];
    #pragma unroll
    for (int s = 0; s < 4; s++) {
        pv0[s] = (float4_t){0.f, 0.f, 0.f, 0.f};
        pv1[s] = (float4_t){0.f, 0.f, 0.f, 0.f};
        dsum[s] = 0.f;
    }
    const float4_t zero4 = (float4_t){0.f, 0.f, 0.f, 0.f};

    int start = (p * 125) >> 1, end = ((p + 1) * 125) >> 1;   // 1000 chunks / 16
    for (int k = start + wave; k < end; k += 4) {
        // QK A-operand (16x16x32: m=lo (vocab row), k=quad*8+j); 16B/lane
        const ushort_t* pa = ST + ((k * 32 + lo) * 32 + quad * 8);
        short8 a0 = *(const short8*)pa;             // v-tile 0 (v0..15)
        short8 a1 = *(const short8*)(pa + 512);     // v-tile 1 (v16..31)
        const ushort_t* pb = S2 + ((size_t)(k * 2) * 64 + lane) * 8;
        short8 sb0 = *(const short8*)pb;            // h 0..15
        short8 sb1 = *(const short8*)(pb + 512);    // h 16..31
        short4_t b00 = {sb0[0], sb0[1], sb0[2], sb0[3]};
        short4_t b01 = {sb0[4], sb0[5], sb0[6], sb0[7]};
        short4_t b10 = {sb1[0], sb1[1], sb1[2], sb1[3]};
        short4_t b11 = {sb1[4], sb1[5], sb1[6], sb1[7]};

        #pragma unroll
        for (int s = 0; s < 4; s++) {
            // logits transposed: D[v][q], C-layout row=v=quad*4+reg, col=q=lo
            float4_t l0 = __builtin_amdgcn_mfma_f32_16x16x32_bf16(a0, qf[s], zero4, 0, 0, 0);
            float4_t l1 = __builtin_amdgcn_mfma_f32_16x16x32_bf16(a1, qf[s], zero4, 0, 0, 0);
            // raw v_exp_f32 (q pre-scaled by log2e/temp)
            float e0 = __builtin_amdgcn_exp2f(l0[0]);
            float e1 = __builtin_amdgcn_exp2f(l0[1]);
            float e2 = __builtin_amdgcn_exp2f(l0[2]);
            float e3 = __builtin_amdgcn_exp2f(l0[3]);
            float f0 = __builtin_amdgcn_exp2f(l1[0]);
            float f1 = __builtin_amdgcn_exp2f(l1[1]);
            float f2 = __builtin_amdgcn_exp2f(l1[2]);
            float f3 = __builtin_amdgcn_exp2f(l1[3]);
            // pack truncated bf16 pairs: u = (hi16(odd)<<16) | hi16(even)
            uint u0 = __builtin_amdgcn_perm(__float_as_uint(e1), __float_as_uint(e0), 0x07060302u);
            uint u1 = __builtin_amdgcn_perm(__float_as_uint(e3), __float_as_uint(e2), 0x07060302u);
            uint u2 = __builtin_amdgcn_perm(__float_as_uint(f1), __float_as_uint(f0), 0x07060302u);
            uint u3 = __builtin_amdgcn_perm(__float_as_uint(f3), __float_as_uint(f2), 0x07060302u);
            // denominator on VALU from the SAME truncated values the MFMA sees
            dsum[s] += __uint_as_float(u0 << 16) + __uint_as_float(u0 & 0xffff0000u)
                     + __uint_as_float(u1 << 16) + __uint_as_float(u1 & 0xffff0000u)
                     + __uint_as_float(u2 << 16) + __uint_as_float(u2 & 0xffff0000u)
                     + __uint_as_float(u3 << 16) + __uint_as_float(u3 & 0xffff0000u);
            union { uint u[2]; short4_t s4; } c0, c1;
            c0.u[0] = u0; c0.u[1] = u1;
            c1.u[0] = u2; c1.u[1] = u3;
            short4_t P0 = c0.s4, P1 = c1.s4;
            // PV: out[q][h] += P[q][v] * S[v][h]  (16x16x16, C reg r == A k=quad*4+r)
            pv0[s] = __builtin_amdgcn_mfma_f32_16x16x16bf16_1k(P0, b00, pv0[s], 0, 0, 0);
            pv0[s] = __builtin_amdgcn_mfma_f32_16x16x16bf16_1k(P1, b01, pv0[s], 0, 0, 0);
            pv1[s] = __builtin_amdgcn_mfma_f32_16x16x16bf16_1k(P0, b10, pv1[s], 0, 0, 0);
            pv1[s] = __builtin_amdgcn_mfma_f32_16x16x16bf16_1k(P1, b11, pv1[s], 0, 0, 0);
        }
    }

    // complete per-q denominator: sum over quads (lanes lo, lo+16, lo+32, lo+48)
    #pragma unroll
    for (int s = 0; s < 4; s++) {
        dsum[s] += __shfl_xor(dsum[s], 16, 64);
        dsum[s] += __shfl_xor(dsum[s], 32, 64);
    }

    // in-block reduction across 4 waves
    __shared__ float red[4][64][9];
    int gp = blockIdx.x;
    for (int s = 0; s < 4; s++) {
        #pragma unroll
        for (int r = 0; r < 4; r++) {
            red[wave][lane][r]     = pv0[s][r];
            red[wave][lane][4 + r] = pv1[s][r];
        }
        red[wave][lane][8] = dsum[s];
        __syncthreads();
        if (wave == 0) {
            #pragma unroll
            for (int r = 0; r < 4; r++) {
                float n0 = 0.f, n1 = 0.f;
                #pragma unroll
                for (int w = 0; w < 4; w++) {
                    n0 += red[w][lane][r];
                    n1 += red[w][lane][4 + r];
                }
                int ql = s * 16 + quad * 4 + r;
                pN[((size_t)gp * 64 + ql) * 32 + lo]      = n0;
                pN[((size_t)gp * 64 + ql) * 32 + 16 + lo] = n1;
            }
            if (quad == 0) {
                float dd = red[0][lane][8] + red[1][lane][8] + red[2][lane][8] + red[3][lane][8];
                pD[gp * 64 + s * 16 + lo] = dd;
            }
        }
        __syncthreads();
    }
}

// K3: reduce proj1 partials, apply refinement gate, emit q2 (bf16, pre-scaled).
__global__ void k_refine(const float* __restrict__ pN, const float* __restrict__ pD,
                         const float* __restrict__ x,
                         const float* __restrict__ Wr, const float* __restrict__ br,
                         const float* __restrict__ Wg, const float* __restrict__ bg,
                         const float* __restrict__ temps, ushort_t* __restrict__ q2) {
    int tid = blockIdx.x * 256 + threadIdx.x;   // 131072
    int i = tid >> 5, h = tid & 31, n = i & 31;
    int g = i >> 6, ql = i & 63;
    float N = 0.f, D = 0.f;
    #pragma unroll
    for (int p = 0; p < 16; p++) {
        N += pN[((size_t)(g * 16 + p) * 64 + ql) * 32 + h];
        D += pD[(g * 16 + p) * 64 + ql];
    }
    float vo = N / D;
    const float* xr = x + i * 32;
    float sr = br[h], sg = bg[h];
    #pragma unroll
    for (int h2 = 0; h2 < 32; h2++) {
        sr += xr[h2] * Wr[h * 32 + h2];
        sg += xr[h2] * Wg[h * 32 + h2];
    }
    float ref  = tanhf(sr);
    float gate = 1.f / (1.f + __expf(-sg));
    float refined = vo * (1.f - gate) + ref * gate;
    q2[tid] = f2bf_rne(refined * (LOG2E / fmaxf(temps[n], 0.1f)));
}

// K5: reduce proj2 partials, write final fp32 output.
__global__ void k_final(const float* __restrict__ pN, const float* __restrict__ pD,
                        float* __restrict__ out) {
    int tid = blockIdx.x * 256 + threadIdx.x;   // 131072
    int i = tid >> 5, h = tid & 31;
    int g = i >> 6, ql = i & 63;
    float N = 0.f, D = 0.f;
    #pragma unroll
    for (int p = 0; p < 16; p++) {
        N += pN[((size_t)(g * 16 + p) * 64 + ql) * 32 + h];
        D += pD[(g * 16 + p) * 64 + ql];
    }
    out[tid] = N / D;
}

extern "C" void kernel_launch(void* const* d_in, const int* in_sizes, int n_in,
                              void* d_out, int out_size, void* d_ws, size_t ws_size,
                              hipStream_t stream) {
    const float* x     = (const float*)d_in[0];
    const float* ve    = (const float*)d_in[1];
    const float* Wf    = (const float*)d_in[2];
    const float* bf    = (const float*)d_in[3];
    const float* temps = (const float*)d_in[4];
    const float* Wr    = (const float*)d_in[5];
    const float* br    = (const float*)d_in[6];
    const float* Wg    = (const float*)d_in[7];
    const float* bg    = (const float*)d_in[8];
    float* out = (float*)d_out;

    char* ws = (char*)d_ws;
    ushort_t* ST = (ushort_t*)ws;                          // 2,048,000 B
    ushort_t* S2 = (ushort_t*)(ws + 2048000);              // 2,048,000 B
    ushort_t* q1 = (ushort_t*)(ws + 4096000);              //   262,144 B
    ushort_t* q2 = (ushort_t*)(ws + 4096000 + 262144);     //   262,144 B
    float* pN = (float*)(ws + 4096000 + 2 * 262144);       // 8,388,608 B
    float* pD = (float*)(ws + 4096000 + 2 * 262144 + 8388608); // 262,144 B

    k_build_st<<<dim3(VOCAB), dim3(256), 0, stream>>>(ve, ST);
    k_build_s2<<<dim3(500), dim3(256), 0, stream>>>(ST, S2);
    k_q1<<<dim3(512), dim3(256), 0, stream>>>(x, Wf, bf, temps, q1);
    k_proj<<<dim3(1024), dim3(256), 0, stream>>>(ST, S2, q1, pN, pD);
    k_refine<<<dim3(512), dim3(256), 0, stream>>>(pN, pD, x, Wr, br, Wg, bg, temps, q2);
    k_proj<<<dim3(1024), dim3(256), 0, stream>>>(ST, S2, q2, pN, pD);
    k_final<<<dim3(512), dim3(256), 0, stream>>>(pN, pD, out);
}